// Round 3
// baseline (652.162 us; speedup 1.0000x reference)
//
#include <hip/hip_runtime.h>

// ConvTranspose4d, stride 2: x[4,64,12^4] (*) w[64,64,3^4] -> out[4,64,25^4]
// R3: keep R2's merged-parity block + dense LDS epilogue (write amp already fixed:
// WRITE 397MB). Attack the new bottleneck: serialization + wave idling.
//  - xtrans prepass: x -> bf16, layout xb[slab][m][ci] (ci contiguous) => in-kernel
//    staging is pure coalesced b128 copy, no f2bf VALU.
//  - static all-wave schedule: 40 tiles (4 parity classes) spread over 8 waves so
//    EVERY wave computes in EVERY k3-group (R2 had 50% waves idle per group).
//  - XOR chunk swizzle on xs/ws (128B rows, no pad): coalesced global, <=2-way LDS.

typedef short bf16x8 __attribute__((ext_vector_type(8)));
typedef float f32x4 __attribute__((ext_vector_type(4)));

__device__ __forceinline__ unsigned short f2bf(float f) {
    unsigned int u = __float_as_uint(f);
    u = (u + 0x7FFFu + ((u >> 16) & 1u)) >> 16;
    return (unsigned short)u;
}

// w[ci][co][kk(81)] fp32 -> wt[kk][co][ci] bf16
__global__ __launch_bounds__(256) void wtrans_kernel(const float* __restrict__ w,
                                                     unsigned short* __restrict__ wt) {
    int tid = blockIdx.x * 256 + threadIdx.x;
    if (tid >= 81 * 64 * 64) return;
    int ci = tid & 63;
    int co = (tid >> 6) & 63;
    int kk = tid >> 12;
    wt[tid] = f2bf(w[(ci * 64 + co) * 81 + kk]);
}

// x[b][ci][i1][i2][i3][i4] f32 -> xb[(b*12+i1)*12+i2][m=i3*12+i4][ci] bf16
__global__ __launch_bounds__(256) void xtrans_kernel(const float* __restrict__ x,
                                                     unsigned short* __restrict__ xb) {
    __shared__ unsigned short ls[144][72];
    int blk = blockIdx.x;                 // = (b*12+i1)*12+i2
    int i2 = blk % 12; int t = blk / 12; int i1 = t % 12; int b = t / 12;
    int tid = threadIdx.x;
    int ci = tid >> 2, sub = tid & 3;
    const float* src = x + (size_t)b * 1327104 + (size_t)ci * 20736 + i1 * 1728 + i2 * 144 + sub * 36;
    #pragma unroll
    for (int q = 0; q < 9; ++q) {
        float4 v = *(const float4*)(src + q * 4);
        #pragma unroll
        for (int u = 0; u < 4; ++u) ls[sub * 36 + q * 4 + u][ci] = f2bf(((const float*)&v)[u]);
    }
    __syncthreads();
    unsigned short* dst = xb + (size_t)blk * 9216;
    for (int c = tid; c < 1152; c += 256) {
        int m = c >> 3, part = c & 7;
        *(bf16x8*)(dst + c * 8) = *(const bf16x8*)((const char*)ls + m * 144 + part * 16);
    }
}

#define XS_BYTES 25088          // [196][64] u16, XOR chunk-swizzled
#define WS_BYTES 24576          // [3][64][64] u16, XOR chunk-swizzled
#define SMEM_BYTES 49664        // stg[16][625] f32 (40000 B) overlays

__global__ __launch_bounds__(512, 4) void convt_mfma_kernel(
        const unsigned short* __restrict__ xb,
        const unsigned short* __restrict__ wt,
        const float* __restrict__ bias,
        float* __restrict__ out) {

    __shared__ __align__(16) char smem[SMEM_BYTES];
    char* xsb = smem;
    char* wsb = smem + XS_BYTES;
    float (*stg)[625] = (float (*)[625])smem;

    // bijective XCD-chunk swizzle (2500 wgs, q=312 r=4)
    int orig = blockIdx.x;
    int xcd = orig & 7, oj = orig >> 3;
    int wg = (xcd < 4 ? xcd * 313 : 1252 + (xcd - 4) * 312) + oj;
    int p2 = wg % 25; int tq = wg / 25;
    int p1 = tq % 25; int b = tq / 25;

    // valid (k,i) taps for dims 1,2 at (p1,p2)
    int i1v[2], k1v[2], n1 = 0;
    { int h = p1 >> 1, q = p1 & 1;
      for (int s = 0; s < 2 - q; ++s) { int i = h - s; if (0 <= i && i < 12) { i1v[n1] = i; k1v[n1] = 2 * s + q; ++n1; } } }
    int i2v[2], k2v[2], n2 = 0;
    { int h = p2 >> 1, q = p2 & 1;
      for (int s = 0; s < 2 - q; ++s) { int i = h - s; if (0 <= i && i < 12) { i2v[n2] = i; k2v[n2] = 2 * s + q; ++n2; } } }
    int ncomb = n1 * n2;

    int tid = threadIdx.x;
    int lane = tid & 63;
    int wave = __builtin_amdgcn_readfirstlane(tid >> 6);
    int n_lo = lane & 15, quad = lane >> 4;

    // static schedule: classes 0..3 = (r3,r4) = (0,0),(0,1),(1,0),(1,1) with
    // 11/10/10/9 N-tiles. Per-group MFMA units balanced (4/4/4 or 4/3..4/4 per wave).
    static const int NSLOT[8] = {4, 4, 5, 5, 5, 5, 6, 6};
    static const signed char SCLS[8][6] = {
        {0,0,2,2,0,0}, {0,0,2,2,0,0}, {0,0,3,3,3,0}, {0,0,3,3,3,0},
        {0,0,3,3,3,0}, {0,1,1,2,2,0}, {1,1,1,1,2,2}, {1,1,1,1,2,2}};
    static const signed char STILE[8][6] = {
        {0,1,0,1,0,0}, {2,3,2,3,0,0}, {4,5,0,1,2,0}, {6,7,3,4,5,0},
        {8,9,6,7,8,0}, {10,0,1,4,5,0}, {2,3,4,5,6,7}, {6,7,8,9,8,9}};

    int ns = NSLOT[wave];
    int use0 = 0, use1 = 0, use2 = 0, use3 = 0;     // per-class presence in this wave
    int rbase[6]; unsigned vis = 0;
    #pragma unroll
    for (int j = 0; j < 6; ++j) {
        int c = SCLS[wave][j], t = STILE[wave][j];
        int r3 = c >> 1, r4 = c & 1;
        int n4 = 13 - r4, N = (13 - r3) * n4;
        int pos = t * 16 + n_lo;
        int cp = pos < N ? pos : N - 1;
        int pe3 = cp / n4, pe4 = cp - pe3 * n4;
        rbase[j] = (pe3 + 1) * 14 + (pe4 + 1);      // packs (pe3,pe4); p34 recovered in epilogue
        if (j < ns) {
            if (pos < N) vis |= 1u << j;
            use0 |= (c == 0); use1 |= (c == 1); use2 |= (c == 2); use3 |= (c == 3);
        }
    }

    // zero xs once (halo rows stay zero; interior rewritten per combo)
    for (int f = tid; f < XS_BYTES / 4; f += 512) ((int*)xsb)[f] = 0;

    // seed accumulators with bias
    f32x4 acc[6][4];
    #pragma unroll
    for (int mt = 0; mt < 4; ++mt) {
        #pragma unroll
        for (int rg = 0; rg < 4; ++rg) {
            float bv = bias[mt * 16 + quad * 4 + rg];
            #pragma unroll
            for (int j = 0; j < 6; ++j) acc[j][mt][rg] = bv;
        }
    }
    __syncthreads();

    for (int c = 0; c < ncomb; ++c) {
        if (c) __syncthreads();          // prev combo compute done with xs/ws
        int c1 = c / n2, c2 = c - (c / n2) * n2;
        int i1 = i1v[c1], k1 = k1v[c1];
        int i2 = i2v[c2], k2 = k2v[c2];

        // stage x slab (coalesced b128; XOR chunk swizzle on dest)
        const unsigned short* xbs = xb + (size_t)((b * 12 + i1) * 12 + i2) * 9216;
        #pragma unroll
        for (int it = 0; it < 3; ++it) {
            int idx = it * 512 + tid;
            if (idx < 1152) {
                bf16x8 v = *(const bf16x8*)(xbs + idx * 8);
                int m = idx >> 3, part = idx & 7;
                int a3 = (m * 2731) >> 15, a4 = m - a3 * 12;   // m/12 exact for m<144
                int r = (a3 + 1) * 14 + a4 + 1;
                *(bf16x8*)(xsb + r * 128 + ((part ^ (r & 7)) << 4)) = v;
            }
        }

        int kb9 = (k1 * 3 + k2) * 9;
        for (int g = 0; g < 3; ++g) {
            if (g) __syncthreads();      // compute g-1 done reading ws
            // stage taps (k3=g, k4=0..2): coalesced b128, XOR chunk swizzle
            const unsigned short* wsrc = wt + (size_t)(kb9 + 3 * g) * 4096;
            #pragma unroll
            for (int it = 0; it < 3; ++it) {
                int idx = it * 512 + tid;
                bf16x8 v = *(const bf16x8*)(wsrc + idx * 8);
                int tap = idx >> 9, rch = idx & 511;
                int co = rch >> 3, part = rch & 7;
                *(bf16x8*)(wsb + tap * 8192 + co * 128 + ((part ^ (co & 7)) << 4)) = v;
            }
            __syncthreads();

            int p = g & 1, s3 = (g - p) >> 1;
            #pragma unroll
            for (int tap = 0; tap < 3; ++tap) {
                const int par = tap & 1;
                int any = par ? (p ? use3 : use1) : (p ? use2 : use0);
                if (!any) continue;
                int s4 = tap >> 1;
                const char* wst = wsb + tap * 8192;
                int need = 2 * p + par;
                #pragma unroll
                for (int kc = 0; kc < 2; ++kc) {
                    int pr = kc * 4 + quad;
                    int pwa = (pr ^ (n_lo & 7)) << 4;          // (n_lo+16m)&7 == n_lo&7
                    bf16x8 a0  = *(const bf16x8*)(wst + n_lo * 128 + pwa);
                    bf16x8 a1  = *(const bf16x8*)(wst + n_lo * 128 + 2048 + pwa);
                    bf16x8 a2  = *(const bf16x8*)(wst + n_lo * 128 + 4096 + pwa);
                    bf16x8 a3v = *(const bf16x8*)(wst + n_lo * 128 + 6144 + pwa);
                    #pragma unroll
                    for (int j = 0; j < 6; ++j) {
                        if (j < ns && SCLS[wave][j] == need) {
                            int row = rbase[j] - s3 * 14 - s4;
                            bf16x8 bb = *(const bf16x8*)(xsb + row * 128 + ((pr ^ (row & 7)) << 4));
                            acc[j][0] = __builtin_amdgcn_mfma_f32_16x16x32_bf16(a0,  bb, acc[j][0], 0, 0, 0);
                            acc[j][1] = __builtin_amdgcn_mfma_f32_16x16x32_bf16(a1,  bb, acc[j][1], 0, 0, 0);
                            acc[j][2] = __builtin_amdgcn_mfma_f32_16x16x32_bf16(a2,  bb, acc[j][2], 0, 0, 0);
                            acc[j][3] = __builtin_amdgcn_mfma_f32_16x16x32_bf16(a3v, bb, acc[j][3], 0, 0, 0);
                        }
                    }
                }
            }
        }
    }

    __syncthreads();   // xs/ws dead; stg overlays

    // epilogue: 4 co-chunks; deposit all classes into stg[16][625]; dense stream-out.
    size_t obase = (size_t)b * 64 * 390625 + (size_t)(p1 * 25 + p2) * 625;
    #pragma unroll
    for (int ch = 0; ch < 4; ++ch) {
        #pragma unroll
        for (int j = 0; j < 6; ++j) {
            if ((vis >> j) & 1) {
                int cc = SCLS[wave][j];
                int r3 = cc >> 1, r4 = cc & 1;
                int rb = rbase[j] - 15;
                int pe3 = (rb * 2341) >> 15;                  // rb/14 exact for rb<182
                int pe4 = rb - 14 * pe3;
                int p34 = (2 * pe3 + r3) * 25 + 2 * pe4 + r4;
                #pragma unroll
                for (int rg = 0; rg < 4; ++rg)
                    stg[quad * 4 + rg][p34] = acc[j][ch][rg];
            }
        }
        __syncthreads();
        for (int idx2 = tid; idx2 < 10000; idx2 += 512) {     // 16 co * 625 pos
            int co_l = idx2 / 625, e = idx2 - 625 * co_l;
            out[obase + (size_t)(ch * 16 + co_l) * 390625 + e] = stg[co_l][e];
        }
        __syncthreads();
    }
}

extern "C" void kernel_launch(void* const* d_in, const int* in_sizes, int n_in,
                              void* d_out, int out_size, void* d_ws, size_t ws_size,
                              hipStream_t stream) {
    const float* x    = (const float*)d_in[0];
    const float* w    = (const float*)d_in[1];
    const float* bias = (const float*)d_in[2];
    float* out = (float*)d_out;
    unsigned short* wt = (unsigned short*)d_ws;       // 81*64*64*2   = 663,552 B
    unsigned short* xbf = wt + 81 * 64 * 64;          // 576*144*64*2 = 10,616,832 B

    wtrans_kernel<<<(81 * 64 * 64 + 255) / 256, 256, 0, stream>>>(w, wt);
    xtrans_kernel<<<576, 256, 0, stream>>>(x, xbf);
    convt_mfma_kernel<<<2500, 512, 0, stream>>>(xbf, wt, bias, out);
}

// Round 4
// 580.892 us; speedup vs baseline: 1.1227x; 1.1227x over previous
//
#include <hip/hip_runtime.h>

// ConvTranspose4d, stride 2: x[4,64,12^4] (*) w[64,64,3^4] -> out[4,64,25^4]
// R4 = R3 with the launch-bounds spill fixed. R3's __launch_bounds__(512,4) capped
// VGPRs at 64 (< the 96 f32 acc[6][4]) -> accumulators spilled to scratch -> +500MB
// HBM traffic (WRITE 711MB, FETCH 237MB) and 312us. Revert to (512,2) (R2's proven
// setting: 116 VGPR, zero spill). Structure kept from R3:
//  - xtrans prepass: x -> bf16 xb[slab][m][ci] => in-kernel staging is coalesced b128.
//  - static all-wave schedule: 40 tiles (4 parity classes) over 8 waves, every wave
//    computes in every k3-group.
//  - XOR chunk swizzle on xs/ws; dense LDS epilogue (write amp stays dead).

typedef short bf16x8 __attribute__((ext_vector_type(8)));
typedef float f32x4 __attribute__((ext_vector_type(4)));

__device__ __forceinline__ unsigned short f2bf(float f) {
    unsigned int u = __float_as_uint(f);
    u = (u + 0x7FFFu + ((u >> 16) & 1u)) >> 16;
    return (unsigned short)u;
}

// w[ci][co][kk(81)] fp32 -> wt[kk][co][ci] bf16
__global__ __launch_bounds__(256) void wtrans_kernel(const float* __restrict__ w,
                                                     unsigned short* __restrict__ wt) {
    int tid = blockIdx.x * 256 + threadIdx.x;
    if (tid >= 81 * 64 * 64) return;
    int ci = tid & 63;
    int co = (tid >> 6) & 63;
    int kk = tid >> 12;
    wt[tid] = f2bf(w[(ci * 64 + co) * 81 + kk]);
}

// x[b][ci][i1][i2][i3][i4] f32 -> xb[(b*12+i1)*12+i2][m=i3*12+i4][ci] bf16
__global__ __launch_bounds__(256) void xtrans_kernel(const float* __restrict__ x,
                                                     unsigned short* __restrict__ xb) {
    __shared__ unsigned short ls[144][72];
    int blk = blockIdx.x;                 // = (b*12+i1)*12+i2
    int i2 = blk % 12; int t = blk / 12; int i1 = t % 12; int b = t / 12;
    int tid = threadIdx.x;
    int ci = tid >> 2, sub = tid & 3;
    const float* src = x + (size_t)b * 1327104 + (size_t)ci * 20736 + i1 * 1728 + i2 * 144 + sub * 36;
    #pragma unroll
    for (int q = 0; q < 9; ++q) {
        float4 v = *(const float4*)(src + q * 4);
        #pragma unroll
        for (int u = 0; u < 4; ++u) ls[sub * 36 + q * 4 + u][ci] = f2bf(((const float*)&v)[u]);
    }
    __syncthreads();
    unsigned short* dst = xb + (size_t)blk * 9216;
    for (int c = tid; c < 1152; c += 256) {
        int m = c >> 3, part = c & 7;
        *(bf16x8*)(dst + c * 8) = *(const bf16x8*)((const char*)ls + m * 144 + part * 16);
    }
}

#define XS_BYTES 25088          // [196][64] u16, XOR chunk-swizzled
#define WS_BYTES 24576          // [3][64][64] u16, XOR chunk-swizzled
#define SMEM_BYTES 49664        // stg[16][625] f32 (40000 B) overlays

__global__ __launch_bounds__(512, 2) void convt_mfma_kernel(
        const unsigned short* __restrict__ xb,
        const unsigned short* __restrict__ wt,
        const float* __restrict__ bias,
        float* __restrict__ out) {

    __shared__ __align__(16) char smem[SMEM_BYTES];
    char* xsb = smem;
    char* wsb = smem + XS_BYTES;
    float (*stg)[625] = (float (*)[625])smem;

    // bijective XCD-chunk swizzle (2500 wgs, q=312 r=4)
    int orig = blockIdx.x;
    int xcd = orig & 7, oj = orig >> 3;
    int wg = (xcd < 4 ? xcd * 313 : 1252 + (xcd - 4) * 312) + oj;
    int p2 = wg % 25; int tq = wg / 25;
    int p1 = tq % 25; int b = tq / 25;

    // valid (k,i) taps for dims 1,2 at (p1,p2)
    int i1v[2], k1v[2], n1 = 0;
    { int h = p1 >> 1, q = p1 & 1;
      for (int s = 0; s < 2 - q; ++s) { int i = h - s; if (0 <= i && i < 12) { i1v[n1] = i; k1v[n1] = 2 * s + q; ++n1; } } }
    int i2v[2], k2v[2], n2 = 0;
    { int h = p2 >> 1, q = p2 & 1;
      for (int s = 0; s < 2 - q; ++s) { int i = h - s; if (0 <= i && i < 12) { i2v[n2] = i; k2v[n2] = 2 * s + q; ++n2; } } }
    int ncomb = n1 * n2;

    int tid = threadIdx.x;
    int lane = tid & 63;
    int wave = __builtin_amdgcn_readfirstlane(tid >> 6);
    int n_lo = lane & 15, quad = lane >> 4;

    // static schedule: classes 0..3 = (r3,r4) = (0,0),(0,1),(1,0),(1,1) with
    // 11/10/10/9 N-tiles. Per-group MFMA units balanced across all 8 waves.
    static const int NSLOT[8] = {4, 4, 5, 5, 5, 5, 6, 6};
    static const signed char SCLS[8][6] = {
        {0,0,2,2,0,0}, {0,0,2,2,0,0}, {0,0,3,3,3,0}, {0,0,3,3,3,0},
        {0,0,3,3,3,0}, {0,1,1,2,2,0}, {1,1,1,1,2,2}, {1,1,1,1,2,2}};
    static const signed char STILE[8][6] = {
        {0,1,0,1,0,0}, {2,3,2,3,0,0}, {4,5,0,1,2,0}, {6,7,3,4,5,0},
        {8,9,6,7,8,0}, {10,0,1,4,5,0}, {2,3,4,5,6,7}, {6,7,8,9,8,9}};

    int ns = NSLOT[wave];
    int use0 = 0, use1 = 0, use2 = 0, use3 = 0;     // per-class presence in this wave
    int rbase[6]; unsigned vis = 0;
    #pragma unroll
    for (int j = 0; j < 6; ++j) {
        int c = SCLS[wave][j], t = STILE[wave][j];
        int r3 = c >> 1, r4 = c & 1;
        int n4 = 13 - r4, N = (13 - r3) * n4;
        int pos = t * 16 + n_lo;
        int cp = pos < N ? pos : N - 1;
        int pe3 = cp / n4, pe4 = cp - pe3 * n4;
        rbase[j] = (pe3 + 1) * 14 + (pe4 + 1);      // packs (pe3,pe4); p34 recovered in epilogue
        if (j < ns) {
            if (pos < N) vis |= 1u << j;
            use0 |= (c == 0); use1 |= (c == 1); use2 |= (c == 2); use3 |= (c == 3);
        }
    }

    // zero xs once (halo rows stay zero; interior rewritten per combo)
    for (int f = tid; f < XS_BYTES / 4; f += 512) ((int*)xsb)[f] = 0;

    // seed accumulators with bias
    f32x4 acc[6][4];
    #pragma unroll
    for (int mt = 0; mt < 4; ++mt) {
        #pragma unroll
        for (int rg = 0; rg < 4; ++rg) {
            float bv = bias[mt * 16 + quad * 4 + rg];
            #pragma unroll
            for (int j = 0; j < 6; ++j) acc[j][mt][rg] = bv;
        }
    }
    __syncthreads();

    for (int c = 0; c < ncomb; ++c) {
        if (c) __syncthreads();          // prev combo compute done with xs/ws
        int c1 = c / n2, c2 = c - (c / n2) * n2;
        int i1 = i1v[c1], k1 = k1v[c1];
        int i2 = i2v[c2], k2 = k2v[c2];

        // stage x slab (coalesced b128; XOR chunk swizzle on dest)
        const unsigned short* xbs = xb + (size_t)((b * 12 + i1) * 12 + i2) * 9216;
        #pragma unroll
        for (int it = 0; it < 3; ++it) {
            int idx = it * 512 + tid;
            if (idx < 1152) {
                bf16x8 v = *(const bf16x8*)(xbs + idx * 8);
                int m = idx >> 3, part = idx & 7;
                int a3 = (m * 2731) >> 15, a4 = m - a3 * 12;   // m/12 exact for m<144
                int r = (a3 + 1) * 14 + a4 + 1;
                *(bf16x8*)(xsb + r * 128 + ((part ^ (r & 7)) << 4)) = v;
            }
        }

        int kb9 = (k1 * 3 + k2) * 9;
        for (int g = 0; g < 3; ++g) {
            if (g) __syncthreads();      // compute g-1 done reading ws
            // stage taps (k3=g, k4=0..2): coalesced b128, XOR chunk swizzle
            const unsigned short* wsrc = wt + (size_t)(kb9 + 3 * g) * 4096;
            #pragma unroll
            for (int it = 0; it < 3; ++it) {
                int idx = it * 512 + tid;
                bf16x8 v = *(const bf16x8*)(wsrc + idx * 8);
                int tap = idx >> 9, rch = idx & 511;
                int co = rch >> 3, part = rch & 7;
                *(bf16x8*)(wsb + tap * 8192 + co * 128 + ((part ^ (co & 7)) << 4)) = v;
            }
            __syncthreads();

            int p = g & 1, s3 = (g - p) >> 1;
            #pragma unroll
            for (int tap = 0; tap < 3; ++tap) {
                const int par = tap & 1;
                int any = par ? (p ? use3 : use1) : (p ? use2 : use0);
                if (!any) continue;
                int s4 = tap >> 1;
                const char* wst = wsb + tap * 8192;
                int need = 2 * p + par;
                #pragma unroll
                for (int kc = 0; kc < 2; ++kc) {
                    int pr = kc * 4 + quad;
                    int pwa = (pr ^ (n_lo & 7)) << 4;          // (n_lo+16m)&7 == n_lo&7
                    bf16x8 a0  = *(const bf16x8*)(wst + n_lo * 128 + pwa);
                    bf16x8 a1  = *(const bf16x8*)(wst + n_lo * 128 + 2048 + pwa);
                    bf16x8 a2  = *(const bf16x8*)(wst + n_lo * 128 + 4096 + pwa);
                    bf16x8 a3v = *(const bf16x8*)(wst + n_lo * 128 + 6144 + pwa);
                    #pragma unroll
                    for (int j = 0; j < 6; ++j) {
                        if (j < ns && SCLS[wave][j] == need) {
                            int row = rbase[j] - s3 * 14 - s4;
                            bf16x8 bb = *(const bf16x8*)(xsb + row * 128 + ((pr ^ (row & 7)) << 4));
                            acc[j][0] = __builtin_amdgcn_mfma_f32_16x16x32_bf16(a0,  bb, acc[j][0], 0, 0, 0);
                            acc[j][1] = __builtin_amdgcn_mfma_f32_16x16x32_bf16(a1,  bb, acc[j][1], 0, 0, 0);
                            acc[j][2] = __builtin_amdgcn_mfma_f32_16x16x32_bf16(a2,  bb, acc[j][2], 0, 0, 0);
                            acc[j][3] = __builtin_amdgcn_mfma_f32_16x16x32_bf16(a3v, bb, acc[j][3], 0, 0, 0);
                        }
                    }
                }
            }
        }
    }

    __syncthreads();   // xs/ws dead; stg overlays

    // epilogue: 4 co-chunks; deposit all classes into stg[16][625]; dense stream-out.
    size_t obase = (size_t)b * 64 * 390625 + (size_t)(p1 * 25 + p2) * 625;
    #pragma unroll
    for (int ch = 0; ch < 4; ++ch) {
        #pragma unroll
        for (int j = 0; j < 6; ++j) {
            if ((vis >> j) & 1) {
                int cc = SCLS[wave][j];
                int r3 = cc >> 1, r4 = cc & 1;
                int rb = rbase[j] - 15;
                int pe3 = (rb * 2341) >> 15;                  // rb/14 exact for rb<182
                int pe4 = rb - 14 * pe3;
                int p34 = (2 * pe3 + r3) * 25 + 2 * pe4 + r4;
                #pragma unroll
                for (int rg = 0; rg < 4; ++rg)
                    stg[quad * 4 + rg][p34] = acc[j][ch][rg];
            }
        }
        __syncthreads();
        for (int idx2 = tid; idx2 < 10000; idx2 += 512) {     // 16 co * 625 pos
            int co_l = idx2 / 625, e = idx2 - 625 * co_l;
            out[obase + (size_t)(ch * 16 + co_l) * 390625 + e] = stg[co_l][e];
        }
        __syncthreads();
    }
}

extern "C" void kernel_launch(void* const* d_in, const int* in_sizes, int n_in,
                              void* d_out, int out_size, void* d_ws, size_t ws_size,
                              hipStream_t stream) {
    const float* x    = (const float*)d_in[0];
    const float* w    = (const float*)d_in[1];
    const float* bias = (const float*)d_in[2];
    float* out = (float*)d_out;
    unsigned short* wt = (unsigned short*)d_ws;       // 81*64*64*2   = 663,552 B
    unsigned short* xbf = wt + 81 * 64 * 64;          // 576*144*64*2 = 10,616,832 B

    wtrans_kernel<<<(81 * 64 * 64 + 255) / 256, 256, 0, stream>>>(w, wt);
    xtrans_kernel<<<576, 256, 0, stream>>>(x, xbf);
    convt_mfma_kernel<<<2500, 512, 0, stream>>>(xbf, wt, bias, out);
}

// Round 5
// 569.920 us; speedup vs baseline: 1.1443x; 1.0193x over previous
//
#include <hip/hip_runtime.h>

// ConvTranspose4d, stride 2: x[4,64,12^4] (*) w[64,64,3^4] -> out[4,64,25^4]
// R5: body redesign to kill latency/VALU binding (R4: no pipe >28%, 55us/block wall
// for ~5us of work). Traffic already clean (FETCH 25MB, WRITE 396MB).
//  - fragment-major weights: wt2[kk][pr][co][8] == MFMA A-frag order. LDS stage =
//    linear copy (precomputed addr); A-reads = 1 address + immediate offsets,
//    conflict-free. (R4 recomputed ~18 VALU of swizzled addresses per MFMA quad.)
//  - ws double-buffer + register prefetch: group g+1's loads issue at phase-g start,
//    land under compute, written after; 4 barriers/combo (was 6-7).
//  - 5-slot schedule: 40 tiles = exactly 5/wave -> acc[5][4]=80 f32, frees VGPRs for
//    prefetch while staying <=128 (2 blocks/CU).
// Epilogue (dense LDS stg + coalesced stream-out) and XCD swizzle unchanged.

typedef short bf16x8 __attribute__((ext_vector_type(8)));
typedef float f32x4 __attribute__((ext_vector_type(4)));

__device__ __forceinline__ unsigned short f2bf(float f) {
    unsigned int u = __float_as_uint(f);
    u = (u + 0x7FFFu + ((u >> 16) & 1u)) >> 16;
    return (unsigned short)u;
}

// w[ci][co][kk(81)] f32 -> wt2[kk][pr(8)][co(64)][u(8)] bf16 (A-fragment-major:
// fragment (pr) covers ci = pr*8+u; lane reads [co][u] as one b128)
__global__ __launch_bounds__(256) void wtrans_kernel(const float* __restrict__ w,
                                                     unsigned short* __restrict__ wt2) {
    int tid = blockIdx.x * 256 + threadIdx.x;
    if (tid >= 81 * 64 * 64) return;
    int u = tid & 7, co = (tid >> 3) & 63, pr = (tid >> 9) & 7, kk = tid >> 12;
    int ci = pr * 8 + u;
    wt2[tid] = f2bf(w[(ci * 64 + co) * 81 + kk]);
}

// x[b][ci][i1][i2][i3][i4] f32 -> xb[(b*12+i1)*12+i2][m=i3*12+i4][ci] bf16
__global__ __launch_bounds__(256) void xtrans_kernel(const float* __restrict__ x,
                                                     unsigned short* __restrict__ xb) {
    __shared__ unsigned short ls[144][72];
    int blk = blockIdx.x;                 // = (b*12+i1)*12+i2
    int i2 = blk % 12; int t = blk / 12; int i1 = t % 12; int b = t / 12;
    int tid = threadIdx.x;
    int ci = tid >> 2, sub = tid & 3;
    const float* src = x + (size_t)b * 1327104 + (size_t)ci * 20736 + i1 * 1728 + i2 * 144 + sub * 36;
    #pragma unroll
    for (int q = 0; q < 9; ++q) {
        float4 v = *(const float4*)(src + q * 4);
        #pragma unroll
        for (int u = 0; u < 4; ++u) ls[sub * 36 + q * 4 + u][ci] = f2bf(((const float*)&v)[u]);
    }
    __syncthreads();
    unsigned short* dst = xb + (size_t)blk * 9216;
    for (int c = tid; c < 1152; c += 256) {
        int m = c >> 3, part = c & 7;
        *(bf16x8*)(dst + c * 8) = *(const bf16x8*)((const char*)ls + m * 144 + part * 16);
    }
}

#define XS_BYTES 25088                     // [196][64] u16, XOR chunk-swizzled
#define WS_HALF  24576                     // [3 taps][8 pr][64 co][8 u16], linear
#define SMEM_BYTES (XS_BYTES + 2 * WS_HALF)   // 74240; stg[16][625] f32 overlays

__global__ __launch_bounds__(512, 2) void convt_mfma_kernel(
        const unsigned short* __restrict__ xb,
        const unsigned short* __restrict__ wt2,
        const float* __restrict__ bias,
        float* __restrict__ out) {

    __shared__ __align__(16) char smem[SMEM_BYTES];
    char* xsb = smem;
    char* wsb = smem + XS_BYTES;
    float (*stg)[625] = (float (*)[625])smem;

    // bijective XCD-chunk swizzle (2500 wgs, q=312 r=4)
    int orig = blockIdx.x;
    int xcd = orig & 7, oj = orig >> 3;
    int wg = (xcd < 4 ? xcd * 313 : 1252 + (xcd - 4) * 312) + oj;
    int p2 = wg % 25; int tq = wg / 25;
    int p1 = tq % 25; int b = tq / 25;

    // valid (k,i) taps for dims 1,2 at (p1,p2)
    int i1v[2], k1v[2], n1 = 0;
    { int h = p1 >> 1, q = p1 & 1;
      for (int s = 0; s < 2 - q; ++s) { int i = h - s; if (0 <= i && i < 12) { i1v[n1] = i; k1v[n1] = 2 * s + q; ++n1; } } }
    int i2v[2], k2v[2], n2 = 0;
    { int h = p2 >> 1, q = p2 & 1;
      for (int s = 0; s < 2 - q; ++s) { int i = h - s; if (0 <= i && i < 12) { i2v[n2] = i; k2v[n2] = 2 * s + q; ++n2; } } }
    int ncomb = n1 * n2;

    int tid = threadIdx.x;
    int lane = tid & 63;
    int wave = __builtin_amdgcn_readfirstlane(tid >> 6);
    int n_lo = lane & 15, quad = lane >> 4;

    // 5-slot schedule: classes (r3,r4)=(0,0),(0,1),(1,0),(1,1) with 11/10/10/9 tiles,
    // exactly 5 slots/wave; per-group MFMA units <= 5/4/5.
    static const signed char SCLS5[8][5] = {
        {0,0,1,2,3},{0,0,1,2,3},{0,0,1,2,3},
        {0,1,1,2,2},{0,1,1,2,2},
        {0,1,2,3,3},{0,1,2,3,3},{0,1,2,3,3}};
    static const signed char STILE5[8][5] = {
        {0,1,0,0,0},{2,3,1,1,1},{4,5,2,2,2},
        {6,3,4,3,4},{7,5,6,5,6},
        {8,7,7,3,4},{9,8,8,5,6},{10,9,9,7,8}};

    int cmask = 0;
    int rb128[5]; unsigned vis = 0;
    #pragma unroll
    for (int j = 0; j < 5; ++j) {
        int cs = SCLS5[wave][j], t = STILE5[wave][j];
        int r3 = cs >> 1, r4 = cs & 1;
        int n4c = 13 - r4, Nc = (13 - r3) * n4c;
        int pos = t * 16 + n_lo;
        int cp = pos < Nc ? pos : Nc - 1;
        int pe3 = cp / n4c, pe4 = cp - pe3 * n4c;
        rb128[j] = ((pe3 + 1) * 14 + (pe4 + 1)) << 7;
        if (pos < Nc) vis |= 1u << j;
        cmask |= 1 << cs;
    }

    // precomputed LDS staging addresses (constant per thread across combos)
    int xsw0, xsw1, xsw2;
    {
        #pragma unroll
        for (int it = 0; it < 3; ++it) {
            int idx = it * 512 + tid;
            int m = idx >> 3, part = idx & 7;
            int a3 = (m * 2731) >> 15, a4 = m - a3 * 12;
            int r = (a3 + 1) * 14 + a4 + 1;
            int v = r * 128 + ((part ^ (r & 7)) << 4);
            if (it == 0) xsw0 = v; else if (it == 1) xsw1 = v; else xsw2 = v;
        }
    }
    int wsw = tid * 16;
    int abase = quad * 1024 + n_lo * 16;   // A-frag per-lane base within a buf

    // zero xs once (halo stays zero; interior rewritten per combo)
    for (int f = tid; f < XS_BYTES / 4; f += 512) ((int*)xsb)[f] = 0;

    // seed accumulators with bias
    f32x4 acc[5][4];
    #pragma unroll
    for (int mt = 0; mt < 4; ++mt) {
        #pragma unroll
        for (int rg = 0; rg < 4; ++rg) {
            float bv = bias[mt * 16 + quad * 4 + rg];
            #pragma unroll
            for (int j = 0; j < 5; ++j) acc[j][mt][rg] = bv;
        }
    }
    __syncthreads();

#define COMPUTE_GROUP(G, WB) do {                                              \
    const int s3_ = (G) >> 1;                                                  \
    _Pragma("unroll")                                                          \
    for (int tap = 0; tap < 3; ++tap) {                                        \
        int need = 2 * ((G) & 1) + (tap & 1), s4 = tap >> 1;                   \
        if (!((cmask >> need) & 1)) continue;                                  \
        const char* wt_ = (WB) + tap * 8192;                                   \
        _Pragma("unroll")                                                      \
        for (int kc = 0; kc < 2; ++kc) {                                       \
            const char* ab = wt_ + kc * 4096 + abase;                          \
            bf16x8 a0  = *(const bf16x8*)(ab);                                 \
            bf16x8 a1  = *(const bf16x8*)(ab + 256);                           \
            bf16x8 a2  = *(const bf16x8*)(ab + 512);                           \
            bf16x8 a3v = *(const bf16x8*)(ab + 768);                           \
            int prq = kc * 4 + quad;                                           \
            _Pragma("unroll")                                                  \
            for (int j = 0; j < 5; ++j) {                                      \
                if (SCLS5[wave][j] == need) {                                  \
                    int row128 = rb128[j] - ((s3_ * 14 + s4) << 7);            \
                    int r7 = (row128 >> 7) & 7;                                \
                    bf16x8 bb = *(const bf16x8*)(xsb + row128 + ((prq ^ r7) << 4)); \
                    acc[j][0] = __builtin_amdgcn_mfma_f32_16x16x32_bf16(a0,  bb, acc[j][0], 0, 0, 0); \
                    acc[j][1] = __builtin_amdgcn_mfma_f32_16x16x32_bf16(a1,  bb, acc[j][1], 0, 0, 0); \
                    acc[j][2] = __builtin_amdgcn_mfma_f32_16x16x32_bf16(a2,  bb, acc[j][2], 0, 0, 0); \
                    acc[j][3] = __builtin_amdgcn_mfma_f32_16x16x32_bf16(a3v, bb, acc[j][3], 0, 0, 0); \
                }                                                              \
            }                                                                  \
        }                                                                      \
    } } while (0)

    for (int c = 0; c < ncomb; ++c) {
        int c1 = c / n2, c2 = c - (c / n2) * n2;
        int i1 = i1v[c1], k1 = k1v[c1];
        int i2 = i2v[c2], k2 = k2v[c2];
        int kb9 = (k1 * 3 + k2) * 9;
        const bf16x8* wgsrc = (const bf16x8*)wt2 + (size_t)kb9 * 512;  // 9 taps x 512

        // issue ws g0 + xs loads, then write both (entry barrier guarantees LDS free)
        bf16x8 wv0 = wgsrc[tid], wv1 = wgsrc[tid + 512], wv2 = wgsrc[tid + 1024];
        const bf16x8* xbs = (const bf16x8*)(xb + (size_t)((b * 12 + i1) * 12 + i2) * 9216);
        bf16x8 x0 = xbs[tid], x1 = xbs[tid + 512];
        bf16x8 x2; if (tid < 128) x2 = xbs[tid + 1024];

        char* wb0 = wsb;
        char* wb1 = wsb + WS_HALF;
        *(bf16x8*)(xsb + xsw0) = x0;
        *(bf16x8*)(xsb + xsw1) = x1;
        if (tid < 128) *(bf16x8*)(xsb + xsw2) = x2;
        *(bf16x8*)(wb0 + wsw)         = wv0;
        *(bf16x8*)(wb0 + wsw + 8192)  = wv1;
        *(bf16x8*)(wb0 + wsw + 16384) = wv2;
        // prefetch g1 (lands under g0 compute)
        wv0 = wgsrc[tid + 1536]; wv1 = wgsrc[tid + 2048]; wv2 = wgsrc[tid + 2560];
        __syncthreads();                       // B1: xs + ws g0 ready

        COMPUTE_GROUP(0, wb0);
        *(bf16x8*)(wb1 + wsw)         = wv0;
        *(bf16x8*)(wb1 + wsw + 8192)  = wv1;
        *(bf16x8*)(wb1 + wsw + 16384) = wv2;
        wv0 = wgsrc[tid + 3072]; wv1 = wgsrc[tid + 3584]; wv2 = wgsrc[tid + 4096];
        __syncthreads();                       // B2: ws g1 ready

        COMPUTE_GROUP(1, wb1);
        *(bf16x8*)(wb0 + wsw)         = wv0;   // g0 readers passed B2 -> buf0 free
        *(bf16x8*)(wb0 + wsw + 8192)  = wv1;
        *(bf16x8*)(wb0 + wsw + 16384) = wv2;
        __syncthreads();                       // B3: ws g2 ready

        COMPUTE_GROUP(2, wb0);
        __syncthreads();                       // B4: xs/ws writable next combo / stg
    }

    // epilogue: 4 co-chunks; deposit all classes into stg[16][625]; dense stream-out.
    size_t obase = (size_t)b * 64 * 390625 + (size_t)(p1 * 25 + p2) * 625;
    #pragma unroll
    for (int ch = 0; ch < 4; ++ch) {
        #pragma unroll
        for (int j = 0; j < 5; ++j) {
            if ((vis >> j) & 1) {
                int cc = SCLS5[wave][j];
                int r3 = cc >> 1, r4 = cc & 1;
                int rb = (rb128[j] >> 7) - 15;
                int pe3 = (rb * 2341) >> 15;               // rb/14 exact for rb<182
                int pe4 = rb - 14 * pe3;
                int p34 = (2 * pe3 + r3) * 25 + 2 * pe4 + r4;
                #pragma unroll
                for (int rg = 0; rg < 4; ++rg)
                    stg[quad * 4 + rg][p34] = acc[j][ch][rg];
            }
        }
        __syncthreads();
        for (int idx2 = tid; idx2 < 10000; idx2 += 512) {  // 16 co * 625 pos
            int co_l = idx2 / 625, e = idx2 - 625 * co_l;
            out[obase + (size_t)(ch * 16 + co_l) * 390625 + e] = stg[co_l][e];
        }
        __syncthreads();
    }
}

extern "C" void kernel_launch(void* const* d_in, const int* in_sizes, int n_in,
                              void* d_out, int out_size, void* d_ws, size_t ws_size,
                              hipStream_t stream) {
    const float* x    = (const float*)d_in[0];
    const float* w    = (const float*)d_in[1];
    const float* bias = (const float*)d_in[2];
    float* out = (float*)d_out;
    unsigned short* wt2 = (unsigned short*)d_ws;      // 81*64*64*2   = 663,552 B
    unsigned short* xbf = wt2 + 81 * 64 * 64;         // 576*144*64*2 = 10,616,832 B

    wtrans_kernel<<<(81 * 64 * 64 + 255) / 256, 256, 0, stream>>>(w, wt2);
    xtrans_kernel<<<576, 256, 0, stream>>>(x, xbf);
    convt_mfma_kernel<<<2500, 512, 0, stream>>>(xbf, wt2, bias, out);
}